// Round 1
// baseline (912.791 us; speedup 1.0000x reference)
//
#include <hip/hip_runtime.h>
#include <cstdint>
#include <cmath>

// ---------------- CSR build ----------------

__global__ void count_kernel(const int* __restrict__ ei, int* __restrict__ counts, int E) {
    int e = blockIdx.x * blockDim.x + threadIdx.x;
    if (e < E) atomicAdd(&counts[ei[E + e]], 1);
}

// single-block chunked exclusive scan: row_ptr, woff (fill cursor copy), dinv = rsqrt(count+1)
__global__ void scan_kernel(const int* __restrict__ counts, int* __restrict__ row_ptr,
                            int* __restrict__ woff, float* __restrict__ dinv, int n) {
    __shared__ int sh[1024];
    int tid = threadIdx.x;
    int chunk = (n + 1023) >> 10;
    int start = tid * chunk;
    int lim = min(start + chunk, n);
    int lsum = 0;
    for (int i = start; i < lim; ++i) lsum += counts[i];
    sh[tid] = lsum;
    __syncthreads();
    for (int off = 1; off < 1024; off <<= 1) {
        int t = (tid >= off) ? sh[tid - off] : 0;
        __syncthreads();
        sh[tid] += t;
        __syncthreads();
    }
    int run = sh[tid] - lsum;  // exclusive base for this thread's chunk
    for (int i = start; i < lim; ++i) {
        int v = counts[i];
        row_ptr[i] = run;
        woff[i] = run;
        dinv[i] = rsqrtf((float)v + 1.0f);  // deg includes self-loop, >= 1
        run += v;
    }
    if (tid == 1023) row_ptr[n] = sh[1023];
}

__global__ void fill_kernel(const int* __restrict__ ei, int* __restrict__ woff,
                            int* __restrict__ colidx, int E) {
    int e = blockIdx.x * blockDim.x + threadIdx.x;
    if (e < E) {
        int src = ei[e];
        int dst = ei[E + e];
        int pos = atomicAdd(&woff[dst], 1);
        colidx[pos] = src;
    }
}

// ---------------- aggregation: out[d] = dinv[d]*(sum_s dinv[s]*in[s] + dinv[d]*in[d]) + b ----

template <int F>
__global__ void agg_kernel(const float* __restrict__ in, float* __restrict__ out,
                           const int* __restrict__ row_ptr, const int* __restrict__ colidx,
                           const float* __restrict__ dinv, const float* __restrict__ bias,
                           int n) {
    int node = blockIdx.x;
    int c = threadIdx.x;
    float dv = dinv[node];
    float acc = dv * in[(size_t)node * F + c];
    int beg = row_ptr[node], end = row_ptr[node + 1];
    for (int k = beg; k < end; ++k) {
        int s = colidx[k];
        acc = fmaf(dinv[s], in[(size_t)s * F + c], acc);
    }
    float r = dv * acc;
    if (bias) r += bias[c];
    out[(size_t)node * F + c] = r;
}

// final layer: aggregate (F=40) + bias + log_softmax, one wave per node
__global__ void agg_softmax_kernel(const float* __restrict__ in, float* __restrict__ out,
                                   const int* __restrict__ row_ptr, const int* __restrict__ colidx,
                                   const float* __restrict__ dinv, const float* __restrict__ b4,
                                   int n) {
    int node = blockIdx.x;
    int c = threadIdx.x;  // 64 threads, 40 active
    float dv = dinv[node];
    float acc = 0.f;
    if (c < 40) acc = dv * in[(size_t)node * 40 + c];
    int beg = row_ptr[node], end = row_ptr[node + 1];
    for (int k = beg; k < end; ++k) {
        int s = colidx[k];
        if (c < 40) acc = fmaf(dinv[s], in[(size_t)s * 40 + c], acc);
    }
    float z = (c < 40) ? (dv * acc + b4[c]) : -INFINITY;
    float m = z;
#pragma unroll
    for (int off = 32; off > 0; off >>= 1) m = fmaxf(m, __shfl_xor(m, off, 64));
    float e = (c < 40) ? expf(z - m) : 0.f;
    float s = e;
#pragma unroll
    for (int off = 32; off > 0; off >>= 1) s += __shfl_xor(s, off, 64);
    if (c < 40) out[(size_t)node * 40 + c] = z - m - logf(s);
}

// ---------------- GEMM: C[M,Nc] = A[M,K] @ W[K,Nc] (+bias) ----------------
// BM=128, BN=64, BK=16, 256 threads, each thread 8x4

#define GBM 128
#define GBN 64
#define GBK 16

__global__ __launch_bounds__(256) void gemm_kernel(const float* __restrict__ A,
                                                   const float* __restrict__ W,
                                                   const float* __restrict__ bias,
                                                   float* __restrict__ C,
                                                   int M, int K, int Nc) {
    __shared__ float As[GBK][GBM + 4];  // stride 132: transposed store, conflict-light
    __shared__ float Bs[GBK][GBN];
    int tid = threadIdx.x;
    int tx = tid & 15, ty = tid >> 4;
    int m0 = blockIdx.x * GBM;
    int n0 = blockIdx.y * GBN;

    float acc[8][4];
#pragma unroll
    for (int i = 0; i < 8; ++i)
#pragma unroll
        for (int j = 0; j < 4; ++j) acc[i][j] = 0.f;

    for (int k0 = 0; k0 < K; k0 += GBK) {
        {   // A tile 128x16: thread t -> k=t&15, rows r=t>>4 (+16i)
            int k = tid & 15;
            int r = tid >> 4;
#pragma unroll
            for (int i = 0; i < 8; ++i) {
                int rr = r + i * 16;
                int gm = m0 + rr;
                As[k][rr] = (gm < M) ? A[(size_t)gm * K + k0 + k] : 0.f;
            }
        }
        {   // B tile 16x64: thread t -> n=t&63, k=t>>6 (+4i)
            int nn = tid & 63;
            int k = tid >> 6;
#pragma unroll
            for (int i = 0; i < 4; ++i) {
                int kk = k + i * 4;
                int gn = n0 + nn;
                Bs[kk][nn] = (gn < Nc) ? W[(size_t)(k0 + kk) * Nc + gn] : 0.f;
            }
        }
        __syncthreads();
#pragma unroll
        for (int kk = 0; kk < GBK; ++kk) {
            float4 a0 = *(const float4*)&As[kk][ty * 8];
            float4 a1 = *(const float4*)&As[kk][ty * 8 + 4];
            float4 b = *(const float4*)&Bs[kk][tx * 4];
            float av[8] = {a0.x, a0.y, a0.z, a0.w, a1.x, a1.y, a1.z, a1.w};
            float bv[4] = {b.x, b.y, b.z, b.w};
#pragma unroll
            for (int i = 0; i < 8; ++i)
#pragma unroll
                for (int j = 0; j < 4; ++j) acc[i][j] = fmaf(av[i], bv[j], acc[i][j]);
        }
        __syncthreads();
    }

#pragma unroll
    for (int i = 0; i < 8; ++i) {
        int gm = m0 + ty * 8 + i;
        if (gm >= M) continue;
#pragma unroll
        for (int j = 0; j < 4; ++j) {
            int gn = n0 + tx * 4 + j;
            if (gn < Nc) {
                float v = acc[i][j];
                if (bias) v += bias[gn];
                C[(size_t)gm * Nc + gn] = v;
            }
        }
    }
}

// ---------------- BatchNorm ----------------

// blockDim = F; grid-stride over rows; sums[c] += sum, sums[256+c] += sumsq
__global__ void stats_kernel(const float* __restrict__ z, float* __restrict__ sums, int n) {
    int F = blockDim.x;
    int c = threadIdx.x;
    float s = 0.f, q = 0.f;
    for (int r = blockIdx.x; r < n; r += gridDim.x) {
        float v = z[(size_t)r * F + c];
        s += v;
        q += v * v;
    }
    atomicAdd(&sums[c], s);
    atomicAdd(&sums[256 + c], q);
}

__global__ void bnfin_kernel(const float* __restrict__ sums, const float* __restrict__ g,
                             const float* __restrict__ be, float* __restrict__ AB, int n, int F) {
    int c = threadIdx.x;
    if (c >= F) return;
    float mean = sums[c] / (float)n;
    float var = sums[256 + c] / (float)n - mean * mean;
    float rstd = rsqrtf(var + 1e-5f);
    float sc = g[c] * rstd;
    AB[c] = sc;
    AB[256 + c] = be[c] - mean * sc;
}

// y = prelu(z*A + B), in place; F is power of two -> mask
__global__ void bnapply_kernel(float* __restrict__ z, const float* __restrict__ AB,
                               const float* __restrict__ pa, int total, int Fmask) {
    float a = pa[0];
    for (int idx = blockIdx.x * blockDim.x + threadIdx.x; idx < total;
         idx += gridDim.x * blockDim.x) {
        int c = idx & Fmask;
        float v = z[idx] * AB[c] + AB[256 + c];
        z[idx] = (v >= 0.f) ? v : a * v;
    }
}

// ---------------- launch ----------------

extern "C" void kernel_launch(void* const* d_in, const int* in_sizes, int n_in,
                              void* d_out, int out_size, void* d_ws, size_t ws_size,
                              hipStream_t stream) {
    const float* x   = (const float*)d_in[0];
    const int*   ei  = (const int*)d_in[1];
    const float* W1  = (const float*)d_in[2];
    const float* b1  = (const float*)d_in[3];
    const float* g1  = (const float*)d_in[4];
    const float* be1 = (const float*)d_in[5];
    const float* W2  = (const float*)d_in[6];
    const float* b2  = (const float*)d_in[7];
    const float* g2  = (const float*)d_in[8];
    const float* be2 = (const float*)d_in[9];
    const float* W3  = (const float*)d_in[10];
    const float* b3  = (const float*)d_in[11];
    const float* g3  = (const float*)d_in[12];
    const float* be3 = (const float*)d_in[13];
    const float* W4  = (const float*)d_in[14];
    const float* b4  = (const float*)d_in[15];
    const float* pa  = (const float*)d_in[16];

    int N = in_sizes[0] / 128;
    int E = in_sizes[1] / 2;

    char* ws = (char*)d_ws;
    size_t off = 0;
    auto carve = [&](size_t bytes) -> char* {
        char* p = ws + off;
        off += (bytes + 255) & ~(size_t)255;
        return p;
    };
    float* dinv    = (float*)carve((size_t)N * 4);
    int*   row_ptr = (int*)carve((size_t)(N + 1) * 4);
    int*   woff    = (int*)carve((size_t)N * 4);
    int*   counts  = (int*)carve((size_t)N * 4);
    int*   colidx  = (int*)carve((size_t)E * 4);
    float* stats   = (float*)carve(512 * 4);
    float* bnAB    = (float*)carve(512 * 4);
    float* bufA    = (float*)carve((size_t)N * 128 * 4);
    float* bufB    = (float*)carve((size_t)N * 256 * 4);
    (void)ws_size; (void)n_in; (void)out_size;

    // CSR build
    hipMemsetAsync(counts, 0, (size_t)N * 4, stream);
    count_kernel<<<(E + 255) / 256, 256, 0, stream>>>(ei, counts, E);
    scan_kernel<<<1, 1024, 0, stream>>>(counts, row_ptr, woff, dinv, N);
    fill_kernel<<<(E + 255) / 256, 256, 0, stream>>>(ei, woff, colidx, E);

    int mb = (N + GBM - 1) / GBM;

    // L1: aggregate x (128 cols) first, then GEMM (+b1): Z1 = (A_hat x) @ W1 + b1
    agg_kernel<128><<<N, 128, 0, stream>>>(x, bufA, row_ptr, colidx, dinv, nullptr, N);
    gemm_kernel<<<dim3(mb, 4), 256, 0, stream>>>(bufA, W1, b1, bufB, N, 128, 256);
    hipMemsetAsync(stats, 0, 512 * 4, stream);
    stats_kernel<<<256, 256, 0, stream>>>(bufB, stats, N);
    bnfin_kernel<<<1, 256, 0, stream>>>(stats, g1, be1, bnAB, N, 256);
    bnapply_kernel<<<2048, 256, 0, stream>>>(bufB, bnAB, pa, N * 256, 255);

    // L2: GEMM first (128 out), then aggregate (+b2)
    gemm_kernel<<<dim3(mb, 2), 256, 0, stream>>>(bufB, W2, nullptr, bufA, N, 256, 128);
    agg_kernel<128><<<N, 128, 0, stream>>>(bufA, bufB, row_ptr, colidx, dinv, b2, N);
    hipMemsetAsync(stats, 0, 512 * 4, stream);
    stats_kernel<<<256, 128, 0, stream>>>(bufB, stats, N);
    bnfin_kernel<<<1, 256, 0, stream>>>(stats, g2, be2, bnAB, N, 128);
    bnapply_kernel<<<2048, 256, 0, stream>>>(bufB, bnAB, pa, N * 128, 127);

    // L3: GEMM (64 out), aggregate (+b3)
    gemm_kernel<<<dim3(mb, 1), 256, 0, stream>>>(bufB, W3, nullptr, bufA, N, 128, 64);
    agg_kernel<64><<<N, 64, 0, stream>>>(bufA, bufB, row_ptr, colidx, dinv, b3, N);
    hipMemsetAsync(stats, 0, 512 * 4, stream);
    stats_kernel<<<256, 64, 0, stream>>>(bufB, stats, N);
    bnfin_kernel<<<1, 256, 0, stream>>>(stats, g3, be3, bnAB, N, 64);
    bnapply_kernel<<<2048, 256, 0, stream>>>(bufB, bnAB, pa, N * 64, 63);

    // L4: GEMM (40 out), aggregate + bias + log_softmax -> d_out
    gemm_kernel<<<dim3(mb, 1), 256, 0, stream>>>(bufB, W4, nullptr, bufA, N, 64, 40);
    agg_softmax_kernel<<<N, 64, 0, stream>>>(bufA, (float*)d_out, row_ptr, colidx, dinv, b4, N);
}

// Round 2
// 764.213 us; speedup vs baseline: 1.1944x; 1.1944x over previous
//
#include <hip/hip_runtime.h>
#include <cstdint>
#include <cmath>

// ---------------- CSR build ----------------

__global__ void count_kernel(const int* __restrict__ ei, int* __restrict__ counts, int E) {
    int e = blockIdx.x * blockDim.x + threadIdx.x;
    if (e < E) atomicAdd(&counts[ei[E + e]], 1);
}

#define SCAN_ELEMS 512  // elements per scan block (256 threads x 2)

// pass 1: per-block sums of counts
__global__ void partsum_kernel(const int* __restrict__ counts, int* __restrict__ bsums, int n) {
    __shared__ int sh[256];
    int b = blockIdx.x, t = threadIdx.x;
    int i0 = b * SCAN_ELEMS + t * 2;
    int s = 0;
    if (i0 < n) s += counts[i0];
    if (i0 + 1 < n) s += counts[i0 + 1];
    sh[t] = s;
    __syncthreads();
    for (int off = 128; off > 0; off >>= 1) {
        if (t < off) sh[t] += sh[t + off];
        __syncthreads();
    }
    if (t == 0) bsums[b] = sh[0];
}

// pass 2: single block, exclusive scan of block sums (nb <= 256); writes row_ptr[n]=total
__global__ void basescan_kernel(int* __restrict__ bsums, int* __restrict__ row_ptr,
                                int nb, int n) {
    __shared__ int sh[256];
    int t = threadIdx.x;
    int v = (t < nb) ? bsums[t] : 0;
    sh[t] = v;
    __syncthreads();
    for (int off = 1; off < 256; off <<= 1) {
        int u = (t >= off) ? sh[t - off] : 0;
        __syncthreads();
        sh[t] += u;
        __syncthreads();
    }
    if (t < nb) bsums[t] = sh[t] - v;  // exclusive base per block
    if (t == 255) row_ptr[n] = sh[255];
}

// pass 3: per-block local exclusive scan + base; writes row_ptr, woff, dinv
__global__ void scanfill_kernel(const int* __restrict__ counts, const int* __restrict__ bsums,
                                int* __restrict__ row_ptr, int* __restrict__ woff,
                                float* __restrict__ dinv, int n) {
    __shared__ int sh[256];
    int b = blockIdx.x, t = threadIdx.x;
    int i0 = b * SCAN_ELEMS + 2 * t;
    int c0 = (i0 < n) ? counts[i0] : 0;
    int c1 = (i0 + 1 < n) ? counts[i0 + 1] : 0;
    int pair = c0 + c1;
    sh[t] = pair;
    __syncthreads();
    for (int off = 1; off < 256; off <<= 1) {
        int u = (t >= off) ? sh[t - off] : 0;
        __syncthreads();
        sh[t] += u;
        __syncthreads();
    }
    int base = bsums[b] + sh[t] - pair;  // exclusive prefix for i0
    if (i0 < n) {
        row_ptr[i0] = base;
        woff[i0] = base;
        dinv[i0] = rsqrtf((float)c0 + 1.0f);
    }
    if (i0 + 1 < n) {
        row_ptr[i0 + 1] = base + c0;
        woff[i0 + 1] = base + c0;
        dinv[i0 + 1] = rsqrtf((float)c1 + 1.0f);
    }
}

__global__ void fill_kernel(const int* __restrict__ ei, int* __restrict__ woff,
                            int* __restrict__ colidx, int E) {
    int e = blockIdx.x * blockDim.x + threadIdx.x;
    if (e < E) {
        int src = ei[e];
        int dst = ei[E + e];
        int pos = atomicAdd(&woff[dst], 1);
        colidx[pos] = src;
    }
}

// ---------------- aggregation: out[d] = dinv[d]*(sum_s dinv[s]*in[s] + dinv[d]*in[d]) + b ----

template <int F>
__global__ void agg_kernel(const float* __restrict__ in, float* __restrict__ out,
                           const int* __restrict__ row_ptr, const int* __restrict__ colidx,
                           const float* __restrict__ dinv, const float* __restrict__ bias,
                           int n) {
    int node = blockIdx.x;
    int c = threadIdx.x;
    float dv = dinv[node];
    float acc = dv * in[(size_t)node * F + c];
    int beg = row_ptr[node], end = row_ptr[node + 1];
    for (int k = beg; k < end; ++k) {
        int s = colidx[k];
        acc = fmaf(dinv[s], in[(size_t)s * F + c], acc);
    }
    float r = dv * acc;
    if (bias) r += bias[c];
    out[(size_t)node * F + c] = r;
}

// final layer: aggregate (F=40) + bias + log_softmax, one wave per node
__global__ void agg_softmax_kernel(const float* __restrict__ in, float* __restrict__ out,
                                   const int* __restrict__ row_ptr, const int* __restrict__ colidx,
                                   const float* __restrict__ dinv, const float* __restrict__ b4,
                                   int n) {
    int node = blockIdx.x;
    int c = threadIdx.x;  // 64 threads, 40 active
    float dv = dinv[node];
    float acc = 0.f;
    if (c < 40) acc = dv * in[(size_t)node * 40 + c];
    int beg = row_ptr[node], end = row_ptr[node + 1];
    for (int k = beg; k < end; ++k) {
        int s = colidx[k];
        if (c < 40) acc = fmaf(dinv[s], in[(size_t)s * 40 + c], acc);
    }
    float z = (c < 40) ? (dv * acc + b4[c]) : -INFINITY;
    float m = z;
#pragma unroll
    for (int off = 32; off > 0; off >>= 1) m = fmaxf(m, __shfl_xor(m, off, 64));
    float e = (c < 40) ? expf(z - m) : 0.f;
    float s = e;
#pragma unroll
    for (int off = 32; off > 0; off >>= 1) s += __shfl_xor(s, off, 64);
    if (c < 40) out[(size_t)node * 40 + c] = z - m - logf(s);
}

// ---------------- GEMM: C[M,Nc] = prelu_bn(A)[M,K] @ W[K,Nc] (+bias) ----------------
// BM=128, BN=64, BK=16, 256 threads, each thread 8x4
// FUSE: A element at column k is transformed v*AB[k]+AB[256+k], then PReLU(alpha)

#define GBM 128
#define GBN 64
#define GBK 16

template <bool FUSE>
__global__ __launch_bounds__(256) void gemm_kernel(const float* __restrict__ A,
                                                   const float* __restrict__ W,
                                                   const float* __restrict__ bias,
                                                   const float* __restrict__ AB,
                                                   const float* __restrict__ pa,
                                                   float* __restrict__ C,
                                                   int M, int K, int Nc) {
    __shared__ float As[GBK][GBM + 4];
    __shared__ float Bs[GBK][GBN];
    int tid = threadIdx.x;
    int tx = tid & 15, ty = tid >> 4;
    int m0 = blockIdx.x * GBM;
    int n0 = blockIdx.y * GBN;
    float alpha = FUSE ? pa[0] : 0.f;

    float acc[8][4];
#pragma unroll
    for (int i = 0; i < 8; ++i)
#pragma unroll
        for (int j = 0; j < 4; ++j) acc[i][j] = 0.f;

    for (int k0 = 0; k0 < K; k0 += GBK) {
        {   // A tile 128x16: thread t -> k=t&15, rows r=t>>4 (+16i)
            int k = tid & 15;
            int r = tid >> 4;
            float sc = 0.f, ofs = 0.f;
            if (FUSE) {
                sc = AB[k0 + k];
                ofs = AB[256 + k0 + k];
            }
#pragma unroll
            for (int i = 0; i < 8; ++i) {
                int rr = r + i * 16;
                int gm = m0 + rr;
                float v = (gm < M) ? A[(size_t)gm * K + k0 + k] : 0.f;
                if (FUSE) {
                    float u = v * sc + ofs;
                    v = (u >= 0.f) ? u : alpha * u;
                }
                As[k][rr] = v;
            }
        }
        {   // B tile 16x64: thread t -> n=t&63, k=t>>6 (+4i)
            int nn = tid & 63;
            int k = tid >> 6;
#pragma unroll
            for (int i = 0; i < 4; ++i) {
                int kk = k + i * 4;
                int gn = n0 + nn;
                Bs[kk][nn] = (gn < Nc) ? W[(size_t)(k0 + kk) * Nc + gn] : 0.f;
            }
        }
        __syncthreads();
#pragma unroll
        for (int kk = 0; kk < GBK; ++kk) {
            float4 a0 = *(const float4*)&As[kk][ty * 8];
            float4 a1 = *(const float4*)&As[kk][ty * 8 + 4];
            float4 b = *(const float4*)&Bs[kk][tx * 4];
            float av[8] = {a0.x, a0.y, a0.z, a0.w, a1.x, a1.y, a1.z, a1.w};
            float bv[4] = {b.x, b.y, b.z, b.w};
#pragma unroll
            for (int i = 0; i < 8; ++i)
#pragma unroll
                for (int j = 0; j < 4; ++j) acc[i][j] = fmaf(av[i], bv[j], acc[i][j]);
        }
        __syncthreads();
    }

#pragma unroll
    for (int i = 0; i < 8; ++i) {
        int gm = m0 + ty * 8 + i;
        if (gm >= M) continue;
#pragma unroll
        for (int j = 0; j < 4; ++j) {
            int gn = n0 + tx * 4 + j;
            if (gn < Nc) {
                float v = acc[i][j];
                if (bias) v += bias[gn];
                C[(size_t)gm * Nc + gn] = v;
            }
        }
    }
}

// ---------------- BatchNorm stats ----------------

// blockDim = F; grid-stride over rows; sums[c] += sum, sums[256+c] += sumsq
__global__ void stats_kernel(const float* __restrict__ z, float* __restrict__ sums, int n) {
    int F = blockDim.x;
    int c = threadIdx.x;
    float s = 0.f, q = 0.f;
    for (int r = blockIdx.x; r < n; r += gridDim.x) {
        float v = z[(size_t)r * F + c];
        s += v;
        q += v * v;
    }
    atomicAdd(&sums[c], s);
    atomicAdd(&sums[256 + c], q);
}

__global__ void bnfin_kernel(const float* __restrict__ sums, const float* __restrict__ g,
                             const float* __restrict__ be, float* __restrict__ AB, int n, int F) {
    int c = threadIdx.x;
    if (c >= F) return;
    float mean = sums[c] / (float)n;
    float var = sums[256 + c] / (float)n - mean * mean;
    float rstd = rsqrtf(var + 1e-5f);
    float sc = g[c] * rstd;
    AB[c] = sc;
    AB[256 + c] = be[c] - mean * sc;
}

// ---------------- launch ----------------

extern "C" void kernel_launch(void* const* d_in, const int* in_sizes, int n_in,
                              void* d_out, int out_size, void* d_ws, size_t ws_size,
                              hipStream_t stream) {
    const float* x   = (const float*)d_in[0];
    const int*   ei  = (const int*)d_in[1];
    const float* W1  = (const float*)d_in[2];
    const float* b1  = (const float*)d_in[3];
    const float* g1  = (const float*)d_in[4];
    const float* be1 = (const float*)d_in[5];
    const float* W2  = (const float*)d_in[6];
    const float* b2  = (const float*)d_in[7];
    const float* g2  = (const float*)d_in[8];
    const float* be2 = (const float*)d_in[9];
    const float* W3  = (const float*)d_in[10];
    const float* b3  = (const float*)d_in[11];
    const float* g3  = (const float*)d_in[12];
    const float* be3 = (const float*)d_in[13];
    const float* W4  = (const float*)d_in[14];
    const float* b4  = (const float*)d_in[15];
    const float* pa  = (const float*)d_in[16];

    int N = in_sizes[0] / 128;
    int E = in_sizes[1] / 2;

    char* ws = (char*)d_ws;
    size_t off = 0;
    auto carve = [&](size_t bytes) -> char* {
        char* p = ws + off;
        off += (bytes + 255) & ~(size_t)255;
        return p;
    };
    int nb = (N + SCAN_ELEMS - 1) / SCAN_ELEMS;  // scan blocks (<=256 supported)
    float* dinv    = (float*)carve((size_t)N * 4);
    int*   row_ptr = (int*)carve((size_t)(N + 1) * 4);
    int*   woff    = (int*)carve((size_t)N * 4);
    int*   counts  = (int*)carve((size_t)N * 4);
    int*   bsums   = (int*)carve((size_t)nb * 4);
    int*   colidx  = (int*)carve((size_t)E * 4);
    float* stats   = (float*)carve(512 * 4);
    float* bnAB    = (float*)carve(512 * 4);
    float* bufA    = (float*)carve((size_t)N * 128 * 4);
    float* bufB    = (float*)carve((size_t)N * 256 * 4);
    (void)ws_size; (void)n_in; (void)out_size;

    // CSR build (parallel scan)
    hipMemsetAsync(counts, 0, (size_t)N * 4, stream);
    count_kernel<<<(E + 255) / 256, 256, 0, stream>>>(ei, counts, E);
    partsum_kernel<<<nb, 256, 0, stream>>>(counts, bsums, N);
    basescan_kernel<<<1, 256, 0, stream>>>(bsums, row_ptr, nb, N);
    scanfill_kernel<<<nb, 256, 0, stream>>>(counts, bsums, row_ptr, woff, dinv, N);
    fill_kernel<<<(E + 255) / 256, 256, 0, stream>>>(ei, woff, colidx, E);

    int mb = (N + GBM - 1) / GBM;

    // L1: aggregate x (128 cols) first, then GEMM (+b1): Z1 = (A_hat x) @ W1 + b1
    agg_kernel<128><<<N, 128, 0, stream>>>(x, bufA, row_ptr, colidx, dinv, nullptr, N);
    gemm_kernel<false><<<dim3(mb, 4), 256, 0, stream>>>(bufA, W1, b1, nullptr, nullptr, bufB,
                                                        N, 128, 256);
    hipMemsetAsync(stats, 0, 512 * 4, stream);
    stats_kernel<<<256, 256, 0, stream>>>(bufB, stats, N);
    bnfin_kernel<<<1, 256, 0, stream>>>(stats, g1, be1, bnAB, N, 256);

    // L2: GEMM (BN1+PReLU fused on A), then aggregate (+b2)
    gemm_kernel<true><<<dim3(mb, 2), 256, 0, stream>>>(bufB, W2, nullptr, bnAB, pa, bufA,
                                                       N, 256, 128);
    agg_kernel<128><<<N, 128, 0, stream>>>(bufA, bufB, row_ptr, colidx, dinv, b2, N);
    hipMemsetAsync(stats, 0, 512 * 4, stream);
    stats_kernel<<<256, 128, 0, stream>>>(bufB, stats, N);
    bnfin_kernel<<<1, 256, 0, stream>>>(stats, g2, be2, bnAB, N, 128);

    // L3: GEMM (BN2+PReLU fused), aggregate (+b3)
    gemm_kernel<true><<<dim3(mb, 1), 256, 0, stream>>>(bufB, W3, nullptr, bnAB, pa, bufA,
                                                       N, 128, 64);
    agg_kernel<64><<<N, 64, 0, stream>>>(bufA, bufB, row_ptr, colidx, dinv, b3, N);
    hipMemsetAsync(stats, 0, 512 * 4, stream);
    stats_kernel<<<256, 64, 0, stream>>>(bufB, stats, N);
    bnfin_kernel<<<1, 256, 0, stream>>>(stats, g3, be3, bnAB, N, 64);

    // L4: GEMM (BN3+PReLU fused, 40 out), aggregate + bias + log_softmax -> d_out
    gemm_kernel<true><<<dim3(mb, 1), 256, 0, stream>>>(bufB, W4, nullptr, bnAB, pa, bufA,
                                                       N, 64, 40);
    agg_softmax_kernel<<<N, 64, 0, stream>>>(bufA, (float*)d_out, row_ptr, colidx, dinv, b4, N);
}

// Round 3
// 676.733 us; speedup vs baseline: 1.3488x; 1.1293x over previous
//
#include <hip/hip_runtime.h>
#include <hip/hip_fp16.h>
#include <cstdint>
#include <cmath>

// ---------------- CSR build ----------------

__global__ void count_kernel(const int* __restrict__ ei, int* __restrict__ counts, int E) {
    int e = blockIdx.x * blockDim.x + threadIdx.x;
    if (e < E) atomicAdd(&counts[ei[E + e]], 1);
}

#define SCAN_ELEMS 512  // elements per scan block (256 threads x 2)

__global__ void partsum_kernel(const int* __restrict__ counts, int* __restrict__ bsums, int n) {
    __shared__ int sh[256];
    int b = blockIdx.x, t = threadIdx.x;
    int i0 = b * SCAN_ELEMS + t * 2;
    int s = 0;
    if (i0 < n) s += counts[i0];
    if (i0 + 1 < n) s += counts[i0 + 1];
    sh[t] = s;
    __syncthreads();
    for (int off = 128; off > 0; off >>= 1) {
        if (t < off) sh[t] += sh[t + off];
        __syncthreads();
    }
    if (t == 0) bsums[b] = sh[0];
}

__global__ void basescan_kernel(int* __restrict__ bsums, int* __restrict__ row_ptr,
                                int nb, int n) {
    __shared__ int sh[256];
    int t = threadIdx.x;
    int v = (t < nb) ? bsums[t] : 0;
    sh[t] = v;
    __syncthreads();
    for (int off = 1; off < 256; off <<= 1) {
        int u = (t >= off) ? sh[t - off] : 0;
        __syncthreads();
        sh[t] += u;
        __syncthreads();
    }
    if (t < nb) bsums[t] = sh[t] - v;
    if (t == 255) row_ptr[n] = sh[255];
}

__global__ void scanfill_kernel(const int* __restrict__ counts, const int* __restrict__ bsums,
                                int* __restrict__ row_ptr, int* __restrict__ woff,
                                float* __restrict__ dinv, int n) {
    __shared__ int sh[256];
    int b = blockIdx.x, t = threadIdx.x;
    int i0 = b * SCAN_ELEMS + 2 * t;
    int c0 = (i0 < n) ? counts[i0] : 0;
    int c1 = (i0 + 1 < n) ? counts[i0 + 1] : 0;
    int pair = c0 + c1;
    sh[t] = pair;
    __syncthreads();
    for (int off = 1; off < 256; off <<= 1) {
        int u = (t >= off) ? sh[t - off] : 0;
        __syncthreads();
        sh[t] += u;
        __syncthreads();
    }
    int base = bsums[b] + sh[t] - pair;
    if (i0 < n) {
        row_ptr[i0] = base;
        woff[i0] = base;
        dinv[i0] = rsqrtf((float)c0 + 1.0f);
    }
    if (i0 + 1 < n) {
        row_ptr[i0 + 1] = base + c0;
        woff[i0 + 1] = base + c0;
        dinv[i0 + 1] = rsqrtf((float)c1 + 1.0f);
    }
}

__global__ void fill_kernel(const int* __restrict__ ei, int* __restrict__ woff,
                            int* __restrict__ colidx, int E) {
    int e = blockIdx.x * blockDim.x + threadIdx.x;
    if (e < E) {
        int src = ei[e];
        int dst = ei[E + e];
        int pos = atomicAdd(&woff[dst], 1);
        colidx[pos] = src;
    }
}

// ---------------- f32 -> fp16 convert ----------------

__global__ void f2h_kernel(const float* __restrict__ x, __half* __restrict__ xh, int total4) {
    int i = blockIdx.x * blockDim.x + threadIdx.x;
    if (i < total4) {
        float4 v = *(const float4*)&x[i * 4];
        __half2 a = __floats2half2_rn(v.x, v.y);
        __half2 b = __floats2half2_rn(v.z, v.w);
        *(__half2*)&xh[i * 4] = a;
        *(__half2*)&xh[i * 4 + 2] = b;
    }
}

// ------- aggregation (fp16 in, f32 out): out[d] = dinv[d]*(sum dinv[s]*in[s] + dinv[d]*in[d]) ----

__global__ void aggh128_kernel(const __half2* __restrict__ in, float* __restrict__ out,
                               const int* __restrict__ row_ptr, const int* __restrict__ colidx,
                               const float* __restrict__ dinv, int n) {
    int node = blockIdx.x;
    int c = threadIdx.x;  // 64 lanes, 2 cols each
    float dv = dinv[node];
    float2 self = __half22float2(in[(size_t)node * 64 + c]);
    float acc0 = dv * self.x, acc1 = dv * self.y;
    int beg = row_ptr[node], end = row_ptr[node + 1];
    for (int k = beg; k < end; ++k) {
        int s = colidx[k];
        float ds = dinv[s];
        float2 v = __half22float2(in[(size_t)s * 64 + c]);
        acc0 = fmaf(ds, v.x, acc0);
        acc1 = fmaf(ds, v.y, acc1);
    }
    size_t o = (size_t)node * 128 + 2 * c;
    out[o] = dv * acc0;
    out[o + 1] = dv * acc1;
}

__global__ void aggh64_kernel(const __half* __restrict__ in, float* __restrict__ out,
                              const int* __restrict__ row_ptr, const int* __restrict__ colidx,
                              const float* __restrict__ dinv, int n) {
    int node = blockIdx.x;
    int c = threadIdx.x;  // 64 lanes, 1 col each
    float dv = dinv[node];
    float acc = dv * __half2float(in[(size_t)node * 64 + c]);
    int beg = row_ptr[node], end = row_ptr[node + 1];
    for (int k = beg; k < end; ++k) {
        int s = colidx[k];
        acc = fmaf(dinv[s], __half2float(in[(size_t)s * 64 + c]), acc);
    }
    out[(size_t)node * 64 + c] = dv * acc;
}

__global__ void aggh_softmax_kernel(const __half* __restrict__ in, float* __restrict__ out,
                                    const int* __restrict__ row_ptr, const int* __restrict__ colidx,
                                    const float* __restrict__ dinv, const float* __restrict__ b4,
                                    int n) {
    int node = blockIdx.x;
    int c = threadIdx.x;  // 64 threads, 40 active
    float dv = dinv[node];
    float acc = 0.f;
    if (c < 40) acc = dv * __half2float(in[(size_t)node * 40 + c]);
    int beg = row_ptr[node], end = row_ptr[node + 1];
    for (int k = beg; k < end; ++k) {
        int s = colidx[k];
        if (c < 40) acc = fmaf(dinv[s], __half2float(in[(size_t)s * 40 + c]), acc);
    }
    float z = (c < 40) ? (dv * acc + b4[c]) : -INFINITY;
    float m = z;
#pragma unroll
    for (int off = 32; off > 0; off >>= 1) m = fmaxf(m, __shfl_xor(m, off, 64));
    float e = (c < 40) ? expf(z - m) : 0.f;
    float s = e;
#pragma unroll
    for (int off = 32; off > 0; off >>= 1) s += __shfl_xor(s, off, 64);
    if (c < 40) out[(size_t)node * 40 + c] = z - m - logf(s);
}

// ---------------- f32 fallback aggregation (used only if ws too small) ----------------

template <int F>
__global__ void agg_kernel(const float* __restrict__ in, float* __restrict__ out,
                           const int* __restrict__ row_ptr, const int* __restrict__ colidx,
                           const float* __restrict__ dinv, int n) {
    int node = blockIdx.x;
    int c = threadIdx.x;
    float dv = dinv[node];
    float acc = dv * in[(size_t)node * F + c];
    int beg = row_ptr[node], end = row_ptr[node + 1];
    for (int k = beg; k < end; ++k) {
        int s = colidx[k];
        acc = fmaf(dinv[s], in[(size_t)s * F + c], acc);
    }
    out[(size_t)node * F + c] = dv * acc;
}

__global__ void agg_softmax_kernel(const float* __restrict__ in, float* __restrict__ out,
                                   const int* __restrict__ row_ptr, const int* __restrict__ colidx,
                                   const float* __restrict__ dinv, const float* __restrict__ b4,
                                   int n) {
    int node = blockIdx.x;
    int c = threadIdx.x;
    float dv = dinv[node];
    float acc = 0.f;
    if (c < 40) acc = dv * in[(size_t)node * 40 + c];
    int beg = row_ptr[node], end = row_ptr[node + 1];
    for (int k = beg; k < end; ++k) {
        int s = colidx[k];
        if (c < 40) acc = fmaf(dinv[s], in[(size_t)s * 40 + c], acc);
    }
    float z = (c < 40) ? (dv * acc + b4[c]) : -INFINITY;
    float m = z;
#pragma unroll
    for (int off = 32; off > 0; off >>= 1) m = fmaxf(m, __shfl_xor(m, off, 64));
    float e = (c < 40) ? expf(z - m) : 0.f;
    float s = e;
#pragma unroll
    for (int off = 32; off > 0; off >>= 1) s += __shfl_xor(s, off, 64);
    if (c < 40) out[(size_t)node * 40 + c] = z - m - logf(s);
}

// ---------------- GEMM: C = prelu_bn(A) @ W, optional fp16 output ----------------

#define GBM 128
#define GBN 64
#define GBK 16

template <bool FUSE, bool OUTH>
__global__ __launch_bounds__(256) void gemm_kernel(const float* __restrict__ A,
                                                   const float* __restrict__ W,
                                                   const float* __restrict__ bias,
                                                   const float* __restrict__ AB,
                                                   const float* __restrict__ pa,
                                                   void* __restrict__ Cv,
                                                   int M, int K, int Nc) {
    __shared__ float As[GBK][GBM + 4];
    __shared__ float Bs[GBK][GBN];
    int tid = threadIdx.x;
    int tx = tid & 15, ty = tid >> 4;
    int m0 = blockIdx.x * GBM;
    int n0 = blockIdx.y * GBN;
    float alpha = FUSE ? pa[0] : 0.f;

    float acc[8][4];
#pragma unroll
    for (int i = 0; i < 8; ++i)
#pragma unroll
        for (int j = 0; j < 4; ++j) acc[i][j] = 0.f;

    for (int k0 = 0; k0 < K; k0 += GBK) {
        {
            int k = tid & 15;
            int r = tid >> 4;
            float sc = 0.f, ofs = 0.f;
            if (FUSE) {
                sc = AB[k0 + k];
                ofs = AB[256 + k0 + k];
            }
#pragma unroll
            for (int i = 0; i < 8; ++i) {
                int rr = r + i * 16;
                int gm = m0 + rr;
                float v = (gm < M) ? A[(size_t)gm * K + k0 + k] : 0.f;
                if (FUSE) {
                    float u = v * sc + ofs;
                    v = (u >= 0.f) ? u : alpha * u;
                }
                As[k][rr] = v;
            }
        }
        {
            int nn = tid & 63;
            int k = tid >> 6;
#pragma unroll
            for (int i = 0; i < 4; ++i) {
                int kk = k + i * 4;
                int gn = n0 + nn;
                Bs[kk][nn] = (gn < Nc) ? W[(size_t)(k0 + kk) * Nc + gn] : 0.f;
            }
        }
        __syncthreads();
#pragma unroll
        for (int kk = 0; kk < GBK; ++kk) {
            float4 a0 = *(const float4*)&As[kk][ty * 8];
            float4 a1 = *(const float4*)&As[kk][ty * 8 + 4];
            float4 b = *(const float4*)&Bs[kk][tx * 4];
            float av[8] = {a0.x, a0.y, a0.z, a0.w, a1.x, a1.y, a1.z, a1.w};
            float bv[4] = {b.x, b.y, b.z, b.w};
#pragma unroll
            for (int i = 0; i < 8; ++i)
#pragma unroll
                for (int j = 0; j < 4; ++j) acc[i][j] = fmaf(av[i], bv[j], acc[i][j]);
        }
        __syncthreads();
    }

#pragma unroll
    for (int i = 0; i < 8; ++i) {
        int gm = m0 + ty * 8 + i;
        if (gm >= M) continue;
#pragma unroll
        for (int j = 0; j < 4; ++j) {
            int gn = n0 + tx * 4 + j;
            if (gn < Nc) {
                float v = acc[i][j];
                if (bias) v += bias[gn];
                if (OUTH)
                    ((__half*)Cv)[(size_t)gm * Nc + gn] = __float2half_rn(v);
                else
                    ((float*)Cv)[(size_t)gm * Nc + gn] = v;
            }
        }
    }
}

// ---------------- BatchNorm stats ----------------

__global__ void stats_kernel(const float* __restrict__ z, float* __restrict__ sums, int n) {
    int F = blockDim.x;
    int c = threadIdx.x;
    float s = 0.f, q = 0.f;
    for (int r = blockIdx.x; r < n; r += gridDim.x) {
        float v = z[(size_t)r * F + c];
        s += v;
        q += v * v;
    }
    atomicAdd(&sums[c], s);
    atomicAdd(&sums[256 + c], q);
}

__global__ void bnfin_kernel(const float* __restrict__ sums, const float* __restrict__ g,
                             const float* __restrict__ be, float* __restrict__ AB, int n, int F) {
    int c = threadIdx.x;
    if (c >= F) return;
    float mean = sums[c] / (float)n;
    float var = sums[256 + c] / (float)n - mean * mean;
    float rstd = rsqrtf(var + 1e-5f);
    float sc = g[c] * rstd;
    AB[c] = sc;
    AB[256 + c] = be[c] - mean * sc;
}

// ---------------- launch ----------------

extern "C" void kernel_launch(void* const* d_in, const int* in_sizes, int n_in,
                              void* d_out, int out_size, void* d_ws, size_t ws_size,
                              hipStream_t stream) {
    const float* x   = (const float*)d_in[0];
    const int*   ei  = (const int*)d_in[1];
    const float* W1  = (const float*)d_in[2];
    const float* g1  = (const float*)d_in[4];
    const float* be1 = (const float*)d_in[5];
    const float* W2  = (const float*)d_in[6];
    const float* g2  = (const float*)d_in[8];
    const float* be2 = (const float*)d_in[9];
    const float* W3  = (const float*)d_in[10];
    const float* g3  = (const float*)d_in[12];
    const float* be3 = (const float*)d_in[13];
    const float* W4  = (const float*)d_in[14];
    const float* b4  = (const float*)d_in[15];
    const float* pa  = (const float*)d_in[16];
    // NOTE: b1,b2,b3 (d_in[3],[7],[11]) are dropped: a per-column constant added
    // immediately before BatchNorm is cancelled exactly by the mean subtraction.

    int N = in_sizes[0] / 128;
    int E = in_sizes[1] / 2;

    char* ws = (char*)d_ws;
    size_t off = 0;
    auto carve = [&](size_t bytes) -> char* {
        char* p = ws + off;
        off += (bytes + 255) & ~(size_t)255;
        return p;
    };
    int nb = (N + SCAN_ELEMS - 1) / SCAN_ELEMS;
    float* dinv    = (float*)carve((size_t)N * 4);
    int*   row_ptr = (int*)carve((size_t)(N + 1) * 4);
    int*   woff    = (int*)carve((size_t)N * 4);
    int*   counts  = (int*)carve((size_t)N * 4);
    int*   bsums   = (int*)carve((size_t)nb * 4);
    int*   colidx  = (int*)carve((size_t)E * 4);
    float* stats   = (float*)carve(512 * 4);
    float* bnAB    = (float*)carve(512 * 4);
    float* P1      = (float*)carve((size_t)N * 128 * 4);  // agg outputs (f32)
    float* P0      = (float*)carve((size_t)N * 256 * 4);  // Z1 (f32); also hosts xh
    size_t need_h = off + ((size_t)N * 128 * 2 + 255);
    bool useh = (need_h <= ws_size);
    __half* P2h = useh ? (__half*)carve((size_t)N * 128 * 2) : nullptr;  // fp16 features
    (void)n_in; (void)out_size;

    // CSR build
    hipMemsetAsync(counts, 0, (size_t)N * 4, stream);
    count_kernel<<<(E + 255) / 256, 256, 0, stream>>>(ei, counts, E);
    partsum_kernel<<<nb, 256, 0, stream>>>(counts, bsums, N);
    basescan_kernel<<<1, 256, 0, stream>>>(bsums, row_ptr, nb, N);
    scanfill_kernel<<<nb, 256, 0, stream>>>(counts, bsums, row_ptr, woff, dinv, N);
    fill_kernel<<<(E + 255) / 256, 256, 0, stream>>>(ei, woff, colidx, E);

    int mb = (N + GBM - 1) / GBM;

    if (useh) {
        __half* xh = (__half*)P0;  // xh dead before gemm1 writes Z1 into P0

        // L1: x->fp16, aggregate (128), GEMM -> Z1 (f32)
        f2h_kernel<<<(N * 128 / 4 + 255) / 256, 256, 0, stream>>>(x, xh, N * 128 / 4);
        aggh128_kernel<<<N, 64, 0, stream>>>((const __half2*)xh, P1, row_ptr, colidx, dinv, N);
        gemm_kernel<false, false><<<dim3(mb, 4), 256, 0, stream>>>(P1, W1, nullptr, nullptr,
                                                                   nullptr, P0, N, 128, 256);
        hipMemsetAsync(stats, 0, 512 * 4, stream);
        stats_kernel<<<256, 256, 0, stream>>>(P0, stats, N);
        bnfin_kernel<<<1, 256, 0, stream>>>(stats, g1, be1, bnAB, N, 256);

        // L2: GEMM (BN1+PReLU fused) -> fp16, aggregate -> Z2 (f32)
        gemm_kernel<true, true><<<dim3(mb, 2), 256, 0, stream>>>(P0, W2, nullptr, bnAB, pa,
                                                                 P2h, N, 256, 128);
        aggh128_kernel<<<N, 64, 0, stream>>>((const __half2*)P2h, P1, row_ptr, colidx, dinv, N);
        hipMemsetAsync(stats, 0, 512 * 4, stream);
        stats_kernel<<<256, 128, 0, stream>>>(P1, stats, N);
        bnfin_kernel<<<1, 256, 0, stream>>>(stats, g2, be2, bnAB, N, 128);

        // L3: GEMM (BN2 fused) -> fp16 (64), aggregate -> Z3 (f32)
        gemm_kernel<true, true><<<dim3(mb, 1), 256, 0, stream>>>(P1, W3, nullptr, bnAB, pa,
                                                                 P2h, N, 128, 64);
        aggh64_kernel<<<N, 64, 0, stream>>>(P2h, P1, row_ptr, colidx, dinv, N);
        hipMemsetAsync(stats, 0, 512 * 4, stream);
        stats_kernel<<<256, 64, 0, stream>>>(P1, stats, N);
        bnfin_kernel<<<1, 256, 0, stream>>>(stats, g3, be3, bnAB, N, 64);

        // L4: GEMM (BN3 fused) -> fp16 (40), aggregate + b4 + log_softmax -> out
        gemm_kernel<true, true><<<dim3(mb, 1), 256, 0, stream>>>(P1, W4, nullptr, bnAB, pa,
                                                                 P2h, N, 64, 40);
        aggh_softmax_kernel<<<N, 64, 0, stream>>>(P2h, (float*)d_out, row_ptr, colidx, dinv,
                                                  b4, N);
    } else {
        // f32 fallback (round-2 structure)
        agg_kernel<128><<<N, 128, 0, stream>>>(x, P1, row_ptr, colidx, dinv, N);
        gemm_kernel<false, false><<<dim3(mb, 4), 256, 0, stream>>>(P1, W1, nullptr, nullptr,
                                                                   nullptr, P0, N, 128, 256);
        hipMemsetAsync(stats, 0, 512 * 4, stream);
        stats_kernel<<<256, 256, 0, stream>>>(P0, stats, N);
        bnfin_kernel<<<1, 256, 0, stream>>>(stats, g1, be1, bnAB, N, 256);

        gemm_kernel<true, false><<<dim3(mb, 2), 256, 0, stream>>>(P0, W2, nullptr, bnAB, pa,
                                                                  P1, N, 256, 128);
        // note: P1 holds GEMM2 out; aggregate into first half of P0 (Z1 dead)
        agg_kernel<128><<<N, 128, 0, stream>>>(P1, P0, row_ptr, colidx, dinv, N);
        hipMemsetAsync(stats, 0, 512 * 4, stream);
        stats_kernel<<<256, 128, 0, stream>>>(P0, stats, N);
        bnfin_kernel<<<1, 256, 0, stream>>>(stats, g2, be2, bnAB, N, 128);

        gemm_kernel<true, false><<<dim3(mb, 1), 256, 0, stream>>>(P0, W3, nullptr, bnAB, pa,
                                                                  P1, N, 128, 64);
        agg_kernel<64><<<N, 64, 0, stream>>>(P1, P0, row_ptr, colidx, dinv, N);
        hipMemsetAsync(stats, 0, 512 * 4, stream);
        stats_kernel<<<256, 64, 0, stream>>>(P0, stats, N);
        bnfin_kernel<<<1, 256, 0, stream>>>(stats, g3, be3, bnAB, N, 64);

        gemm_kernel<true, false><<<dim3(mb, 1), 256, 0, stream>>>(P0, W4, nullptr, bnAB, pa,
                                                                  P1, N, 64, 40);
        agg_softmax_kernel<<<N, 64, 0, stream>>>(P1, (float*)d_out, row_ptr, colidx, dinv,
                                                 b4, N);
    }
}

// Round 4
// 572.206 us; speedup vs baseline: 1.5952x; 1.1827x over previous
//
#include <hip/hip_runtime.h>
#include <cstdint>
#include <cmath>

typedef _Float16 half_t;
typedef _Float16 h2 __attribute__((ext_vector_type(2)));
typedef _Float16 h8 __attribute__((ext_vector_type(8)));
typedef float f4 __attribute__((ext_vector_type(4)));

// ---------------- CSR build ----------------

__global__ void count_kernel(const int* __restrict__ ei, int* __restrict__ counts, int E) {
    int e = blockIdx.x * blockDim.x + threadIdx.x;
    if (e < E) atomicAdd(&counts[ei[E + e]], 1);
}

#define SCAN_ELEMS 512

__global__ void partsum_kernel(const int* __restrict__ counts, int* __restrict__ bsums, int n) {
    __shared__ int sh[256];
    int b = blockIdx.x, t = threadIdx.x;
    int i0 = b * SCAN_ELEMS + t * 2;
    int s = 0;
    if (i0 < n) s += counts[i0];
    if (i0 + 1 < n) s += counts[i0 + 1];
    sh[t] = s;
    __syncthreads();
    for (int off = 128; off > 0; off >>= 1) {
        if (t < off) sh[t] += sh[t + off];
        __syncthreads();
    }
    if (t == 0) bsums[b] = sh[0];
}

__global__ void basescan_kernel(int* __restrict__ bsums, int* __restrict__ row_ptr,
                                int nb, int n) {
    __shared__ int sh[256];
    int t = threadIdx.x;
    int v = (t < nb) ? bsums[t] : 0;
    sh[t] = v;
    __syncthreads();
    for (int off = 1; off < 256; off <<= 1) {
        int u = (t >= off) ? sh[t - off] : 0;
        __syncthreads();
        sh[t] += u;
        __syncthreads();
    }
    if (t < nb) bsums[t] = sh[t] - v;
    if (t == 255) row_ptr[n] = sh[255];
}

__global__ void scanfill_kernel(const int* __restrict__ counts, const int* __restrict__ bsums,
                                int* __restrict__ row_ptr, int* __restrict__ woff,
                                float* __restrict__ dinv, int n) {
    __shared__ int sh[256];
    int b = blockIdx.x, t = threadIdx.x;
    int i0 = b * SCAN_ELEMS + 2 * t;
    int c0 = (i0 < n) ? counts[i0] : 0;
    int c1 = (i0 + 1 < n) ? counts[i0 + 1] : 0;
    int pair = c0 + c1;
    sh[t] = pair;
    __syncthreads();
    for (int off = 1; off < 256; off <<= 1) {
        int u = (t >= off) ? sh[t - off] : 0;
        __syncthreads();
        sh[t] += u;
        __syncthreads();
    }
    int base = bsums[b] + sh[t] - pair;
    if (i0 < n) {
        row_ptr[i0] = base;
        woff[i0] = base;
        dinv[i0] = rsqrtf((float)c0 + 1.0f);
    }
    if (i0 + 1 < n) {
        row_ptr[i0 + 1] = base + c0;
        woff[i0 + 1] = base + c0;
        dinv[i0 + 1] = rsqrtf((float)c1 + 1.0f);
    }
}

__global__ void fill_kernel(const int* __restrict__ ei, int* __restrict__ woff,
                            int* __restrict__ colidx, int E) {
    int e = blockIdx.x * blockDim.x + threadIdx.x;
    if (e < E) {
        int src = ei[e];
        int dst = ei[E + e];
        int pos = atomicAdd(&woff[dst], 1);
        colidx[pos] = src;
    }
}

// ---------------- conversions ----------------

__global__ void f2h_kernel(const float* __restrict__ x, half_t* __restrict__ xh, int total4) {
    int i = blockIdx.x * blockDim.x + threadIdx.x;
    if (i < total4) {
        float4 v = *(const float4*)&x[i * 4];
        h8* dst = nullptr; (void)dst;
        half_t* p = xh + (size_t)i * 4;
        p[0] = (half_t)v.x; p[1] = (half_t)v.y; p[2] = (half_t)v.z; p[3] = (half_t)v.w;
    }
}

// Wt[n][k] = W[k][n], fp16, n zero-padded to Ncp
__global__ void wt_kernel(const float* __restrict__ W, half_t* __restrict__ Wt,
                          int K, int Nc, int Ncp) {
    int idx = blockIdx.x * blockDim.x + threadIdx.x;
    if (idx >= Ncp * K) return;
    int n = idx / K, k = idx - n * K;
    Wt[idx] = (n < Nc) ? (half_t)W[(size_t)k * Nc + n] : (half_t)0.f;
}

// ------- aggregation (fp16 in, fp16 out): out[d] = dinv[d]*(sum dinv[s]*in[s] + dinv[d]*in[d]) ----

__global__ void aggh128_kernel(const half_t* __restrict__ in, half_t* __restrict__ out,
                               const int* __restrict__ row_ptr, const int* __restrict__ colidx,
                               const float* __restrict__ dinv, int n) {
    int node = blockIdx.x;
    int c = threadIdx.x;  // 64 lanes, 2 cols each
    float dv = dinv[node];
    h2 self = *(const h2*)(in + (size_t)node * 128 + 2 * c);
    float acc0 = dv * (float)self[0], acc1 = dv * (float)self[1];
    int beg = row_ptr[node], end = row_ptr[node + 1];
    for (int k = beg; k < end; ++k) {
        int s = colidx[k];
        float ds = dinv[s];
        h2 v = *(const h2*)(in + (size_t)s * 128 + 2 * c);
        acc0 = fmaf(ds, (float)v[0], acc0);
        acc1 = fmaf(ds, (float)v[1], acc1);
    }
    h2 r;
    r[0] = (half_t)(dv * acc0);
    r[1] = (half_t)(dv * acc1);
    *(h2*)(out + (size_t)node * 128 + 2 * c) = r;
}

__global__ void aggh64_kernel(const half_t* __restrict__ in, half_t* __restrict__ out,
                              const int* __restrict__ row_ptr, const int* __restrict__ colidx,
                              const float* __restrict__ dinv, int n) {
    int node = blockIdx.x;
    int c = threadIdx.x;
    float dv = dinv[node];
    float acc = dv * (float)in[(size_t)node * 64 + c];
    int beg = row_ptr[node], end = row_ptr[node + 1];
    for (int k = beg; k < end; ++k) {
        int s = colidx[k];
        acc = fmaf(dinv[s], (float)in[(size_t)s * 64 + c], acc);
    }
    out[(size_t)node * 64 + c] = (half_t)(dv * acc);
}

__global__ void aggh_softmax_kernel(const half_t* __restrict__ in, float* __restrict__ out,
                                    const int* __restrict__ row_ptr, const int* __restrict__ colidx,
                                    const float* __restrict__ dinv, const float* __restrict__ b4,
                                    int n) {
    int node = blockIdx.x;
    int c = threadIdx.x;  // 64 threads, 40 active
    float dv = dinv[node];
    float acc = 0.f;
    if (c < 40) acc = dv * (float)in[(size_t)node * 40 + c];
    int beg = row_ptr[node], end = row_ptr[node + 1];
    for (int k = beg; k < end; ++k) {
        int s = colidx[k];
        if (c < 40) acc = fmaf(dinv[s], (float)in[(size_t)s * 40 + c], acc);
    }
    float z = (c < 40) ? (dv * acc + b4[c]) : -INFINITY;
    float m = z;
#pragma unroll
    for (int off = 32; off > 0; off >>= 1) m = fmaxf(m, __shfl_xor(m, off, 64));
    float e = (c < 40) ? expf(z - m) : 0.f;
    float s = e;
#pragma unroll
    for (int off = 32; off > 0; off >>= 1) s += __shfl_xor(s, off, 64);
    if (c < 40) out[(size_t)node * 40 + c] = z - m - logf(s);
}

// ---------------- MFMA GEMM: C[M,Nc] = prelu_bn(A)[M,K] @ W[K,Nc], all fp16, f32 accum -----
// LDS-free. Block = 256 threads = 4 waves; each wave computes 16 rows x Nc cols.
// A frag: lane holds row (lane&15), k = (lane>>4)*8 + j  (16B contiguous load)
// B frag: lane holds col (lane&15) of Wt[n][k] (transposed weights), same k pattern
// D:      col = lane&15, row = (lane>>4)*4 + reg   [m89-verified]

template <int K, int NT, bool FUSE>
__global__ __launch_bounds__(256) void mgemm_kernel(const half_t* __restrict__ A,
                                                    const half_t* __restrict__ Wt,  // [NT*16][K]
                                                    const float* __restrict__ AB,
                                                    const float* __restrict__ pa,
                                                    half_t* __restrict__ C,
                                                    int M, int Nc) {
    int wave = threadIdx.x >> 6;
    int lane = threadIdx.x & 63;
    int r0 = blockIdx.x * 64 + wave * 16;
    int arow = r0 + (lane & 15);
    int kgrp = lane >> 4;
    float alpha = FUSE ? pa[0] : 0.f;

    h8 af[K / 32];
    bool rowok = (arow < M);
    const half_t* Ap = A + (size_t)arow * K + kgrp * 8;
#pragma unroll
    for (int kk = 0; kk < K / 32; ++kk) {
        h8 v;
        if (rowok) {
            v = *(const h8*)(Ap + kk * 32);
        } else {
#pragma unroll
            for (int j = 0; j < 8; ++j) v[j] = (half_t)0.f;
        }
        if (FUSE) {
            int kb = kk * 32 + kgrp * 8;
#pragma unroll
            for (int j = 0; j < 8; ++j) {
                float u = (float)v[j] * AB[kb + j] + AB[256 + kb + j];
                u = (u >= 0.f) ? u : alpha * u;
                v[j] = (half_t)u;
            }
        }
        af[kk] = v;
    }

#pragma unroll 1
    for (int nt = 0; nt < NT; ++nt) {
        f4 acc = {0.f, 0.f, 0.f, 0.f};
        const half_t* Wp = Wt + (size_t)(nt * 16 + (lane & 15)) * K + kgrp * 8;
#pragma unroll
        for (int kk = 0; kk < K / 32; ++kk) {
            h8 bf = *(const h8*)(Wp + kk * 32);
            acc = __builtin_amdgcn_mfma_f32_16x16x32_f16(af[kk], bf, acc, 0, 0, 0);
        }
        int col = nt * 16 + (lane & 15);
        if (col < Nc) {
#pragma unroll
            for (int j = 0; j < 4; ++j) {
                int row = r0 + kgrp * 4 + j;
                if (row < M) C[(size_t)row * Nc + col] = (half_t)acc[j];
            }
        }
    }
}

// ---------------- BatchNorm stats (fp16 input) ----------------

__global__ void statsh_kernel(const half_t* __restrict__ z, float* __restrict__ sums, int n) {
    int F = blockDim.x;
    int c = threadIdx.x;
    float s = 0.f, q = 0.f;
    for (int r = blockIdx.x; r < n; r += gridDim.x) {
        float v = (float)z[(size_t)r * F + c];
        s += v;
        q += v * v;
    }
    atomicAdd(&sums[c], s);
    atomicAdd(&sums[256 + c], q);
}

__global__ void bnfin_kernel(const float* __restrict__ sums, const float* __restrict__ g,
                             const float* __restrict__ be, float* __restrict__ AB, int n, int F) {
    int c = threadIdx.x;
    if (c >= F) return;
    float mean = sums[c] / (float)n;
    float var = sums[256 + c] / (float)n - mean * mean;
    float rstd = rsqrtf(var + 1e-5f);
    float sc = g[c] * rstd;
    AB[c] = sc;
    AB[256 + c] = be[c] - mean * sc;
}

// ---------------- launch ----------------

extern "C" void kernel_launch(void* const* d_in, const int* in_sizes, int n_in,
                              void* d_out, int out_size, void* d_ws, size_t ws_size,
                              hipStream_t stream) {
    const float* x   = (const float*)d_in[0];
    const int*   ei  = (const int*)d_in[1];
    const float* W1  = (const float*)d_in[2];
    const float* g1  = (const float*)d_in[4];
    const float* be1 = (const float*)d_in[5];
    const float* W2  = (const float*)d_in[6];
    const float* g2  = (const float*)d_in[8];
    const float* be2 = (const float*)d_in[9];
    const float* W3  = (const float*)d_in[10];
    const float* g3  = (const float*)d_in[12];
    const float* be3 = (const float*)d_in[13];
    const float* W4  = (const float*)d_in[14];
    const float* b4  = (const float*)d_in[15];
    const float* pa  = (const float*)d_in[16];
    // b1,b2,b3 dropped: constants before BatchNorm cancel exactly in mean subtraction.

    int N = in_sizes[0] / 128;
    int E = in_sizes[1] / 2;

    char* ws = (char*)d_ws;
    size_t off = 0;
    auto carve = [&](size_t bytes) -> char* {
        char* p = ws + off;
        off += (bytes + 255) & ~(size_t)255;
        return p;
    };
    int nb = (N + SCAN_ELEMS - 1) / SCAN_ELEMS;
    float*  dinv    = (float*)carve((size_t)N * 4);
    int*    row_ptr = (int*)carve((size_t)(N + 1) * 4);
    int*    woff    = (int*)carve((size_t)N * 4);
    int*    counts  = (int*)carve((size_t)N * 4);
    int*    bsums   = (int*)carve((size_t)nb * 4);
    int*    colidx  = (int*)carve((size_t)E * 4);
    float*  stats   = (float*)carve(512 * 4);
    float*  bnAB    = (float*)carve(512 * 4);
    half_t* W1t     = (half_t*)carve((size_t)256 * 128 * 2);
    half_t* W2t     = (half_t*)carve((size_t)128 * 256 * 2);
    half_t* W3t     = (half_t*)carve((size_t)64 * 128 * 2);
    half_t* W4t     = (half_t*)carve((size_t)48 * 64 * 2);
    half_t* hA      = (half_t*)carve((size_t)N * 256 * 2);  // Z1
    half_t* hB      = (half_t*)carve((size_t)N * 128 * 2);  // xh, P2
    half_t* hC      = (half_t*)carve((size_t)N * 128 * 2);  // P1, Z2
    half_t* hD1     = (half_t*)carve((size_t)N * 64 * 2);   // P3
    half_t* hD2     = (half_t*)carve((size_t)N * 64 * 2);   // Z3
    half_t* hE      = (half_t*)carve((size_t)N * 40 * 2);   // P4
    (void)n_in; (void)out_size; (void)ws_size;

    // CSR build
    hipMemsetAsync(counts, 0, (size_t)N * 4, stream);
    count_kernel<<<(E + 255) / 256, 256, 0, stream>>>(ei, counts, E);
    partsum_kernel<<<nb, 256, 0, stream>>>(counts, bsums, N);
    basescan_kernel<<<1, 256, 0, stream>>>(bsums, row_ptr, nb, N);
    scanfill_kernel<<<nb, 256, 0, stream>>>(counts, bsums, row_ptr, woff, dinv, N);
    fill_kernel<<<(E + 255) / 256, 256, 0, stream>>>(ei, woff, colidx, E);

    // weight convert+transpose (fp16)
    wt_kernel<<<(256 * 128 + 255) / 256, 256, 0, stream>>>(W1, W1t, 128, 256, 256);
    wt_kernel<<<(128 * 256 + 255) / 256, 256, 0, stream>>>(W2, W2t, 256, 128, 128);
    wt_kernel<<<(64 * 128 + 255) / 256, 256, 0, stream>>>(W3, W3t, 128, 64, 64);
    wt_kernel<<<(48 * 64 + 255) / 256, 256, 0, stream>>>(W4, W4t, 64, 40, 48);

    int gb = (N + 63) / 64;  // mgemm blocks

    // L1: x->fp16, aggregate(128), MFMA GEMM -> Z1 fp16 [N,256]
    f2h_kernel<<<(N * 128 / 4 + 255) / 256, 256, 0, stream>>>(x, hB, N * 128 / 4);
    aggh128_kernel<<<N, 64, 0, stream>>>(hB, hC, row_ptr, colidx, dinv, N);
    mgemm_kernel<128, 16, false><<<gb, 256, 0, stream>>>(hC, W1t, nullptr, nullptr, hA, N, 256);
    hipMemsetAsync(stats, 0, 512 * 4, stream);
    statsh_kernel<<<256, 256, 0, stream>>>(hA, stats, N);
    bnfin_kernel<<<1, 256, 0, stream>>>(stats, g1, be1, bnAB, N, 256);

    // L2: GEMM (BN1+PReLU fused) -> P2 fp16 [N,128], aggregate -> Z2
    mgemm_kernel<256, 8, true><<<gb, 256, 0, stream>>>(hA, W2t, bnAB, pa, hB, N, 128);
    aggh128_kernel<<<N, 64, 0, stream>>>(hB, hC, row_ptr, colidx, dinv, N);
    hipMemsetAsync(stats, 0, 512 * 4, stream);
    statsh_kernel<<<256, 128, 0, stream>>>(hC, stats, N);
    bnfin_kernel<<<1, 256, 0, stream>>>(stats, g2, be2, bnAB, N, 128);

    // L3: GEMM (BN2 fused) -> P3 [N,64], aggregate -> Z3
    mgemm_kernel<128, 4, true><<<gb, 256, 0, stream>>>(hC, W3t, bnAB, pa, hD1, N, 64);
    aggh64_kernel<<<N, 64, 0, stream>>>(hD1, hD2, row_ptr, colidx, dinv, N);
    hipMemsetAsync(stats, 0, 512 * 4, stream);
    statsh_kernel<<<256, 64, 0, stream>>>(hD2, stats, N);
    bnfin_kernel<<<1, 256, 0, stream>>>(stats, g3, be3, bnAB, N, 64);

    // L4: GEMM (BN3 fused) -> P4 [N,40], aggregate + b4 + log_softmax -> out (f32)
    mgemm_kernel<64, 3, true><<<gb, 256, 0, stream>>>(hD2, W4t, bnAB, pa, hE, N, 40);
    aggh_softmax_kernel<<<N, 64, 0, stream>>>(hE, (float*)d_out, row_ptr, colidx, dinv, b4, N);
}

// Round 5
// 477.741 us; speedup vs baseline: 1.9106x; 1.1977x over previous
//
#include <hip/hip_runtime.h>
#include <cstdint>
#include <cmath>

typedef _Float16 half_t;
typedef _Float16 h2 __attribute__((ext_vector_type(2)));
typedef _Float16 h8 __attribute__((ext_vector_type(8)));
typedef float f4 __attribute__((ext_vector_type(4)));

// ---------------- CSR build ----------------

__global__ void count_kernel(const int* __restrict__ ei, int* __restrict__ counts, int E) {
    int e = blockIdx.x * blockDim.x + threadIdx.x;
    if (e < E) atomicAdd(&counts[ei[E + e]], 1);
}

#define SCAN_ELEMS 512

__global__ void partsum_kernel(const int* __restrict__ counts, int* __restrict__ bsums, int n) {
    __shared__ int sh[256];
    int b = blockIdx.x, t = threadIdx.x;
    int i0 = b * SCAN_ELEMS + t * 2;
    int s = 0;
    if (i0 < n) s += counts[i0];
    if (i0 + 1 < n) s += counts[i0 + 1];
    sh[t] = s;
    __syncthreads();
    for (int off = 128; off > 0; off >>= 1) {
        if (t < off) sh[t] += sh[t + off];
        __syncthreads();
    }
    if (t == 0) bsums[b] = sh[0];
}

__global__ void basescan_kernel(int* __restrict__ bsums, int* __restrict__ row_ptr,
                                int nb, int n) {
    __shared__ int sh[256];
    int t = threadIdx.x;
    int v = (t < nb) ? bsums[t] : 0;
    sh[t] = v;
    __syncthreads();
    for (int off = 1; off < 256; off <<= 1) {
        int u = (t >= off) ? sh[t - off] : 0;
        __syncthreads();
        sh[t] += u;
        __syncthreads();
    }
    if (t < nb) bsums[t] = sh[t] - v;
    if (t == 255) row_ptr[n] = sh[255];
}

__global__ void scanfill_kernel(const int* __restrict__ counts, const int* __restrict__ bsums,
                                int* __restrict__ row_ptr, int* __restrict__ woff,
                                float* __restrict__ dinv, int n) {
    __shared__ int sh[256];
    int b = blockIdx.x, t = threadIdx.x;
    int i0 = b * SCAN_ELEMS + 2 * t;
    int c0 = (i0 < n) ? counts[i0] : 0;
    int c1 = (i0 + 1 < n) ? counts[i0 + 1] : 0;
    int pair = c0 + c1;
    sh[t] = pair;
    __syncthreads();
    for (int off = 1; off < 256; off <<= 1) {
        int u = (t >= off) ? sh[t - off] : 0;
        __syncthreads();
        sh[t] += u;
        __syncthreads();
    }
    int base = bsums[b] + sh[t] - pair;
    if (i0 < n) {
        row_ptr[i0] = base;
        woff[i0] = base;
        dinv[i0] = rsqrtf((float)c0 + 1.0f);
    }
    if (i0 + 1 < n) {
        row_ptr[i0 + 1] = base + c0;
        woff[i0 + 1] = base + c0;
        dinv[i0 + 1] = rsqrtf((float)c1 + 1.0f);
    }
}

__global__ void fill_kernel(const int* __restrict__ ei, int* __restrict__ woff,
                            int* __restrict__ colidx, int E) {
    int e = blockIdx.x * blockDim.x + threadIdx.x;
    if (e < E) {
        int src = ei[e];
        int dst = ei[E + e];
        int pos = atomicAdd(&woff[dst], 1);
        colidx[pos] = src;
    }
}

// ---------------- conversions ----------------

__global__ void f2h_kernel(const float* __restrict__ x, half_t* __restrict__ xh, int total4) {
    int i = blockIdx.x * blockDim.x + threadIdx.x;
    if (i < total4) {
        float4 v = *(const float4*)&x[i * 4];
        half_t* p = xh + (size_t)i * 4;
        p[0] = (half_t)v.x; p[1] = (half_t)v.y; p[2] = (half_t)v.z; p[3] = (half_t)v.w;
    }
}

// Wt[n][k] = W[k][n], fp16, n zero-padded to Ncp
__global__ void wt_kernel(const float* __restrict__ W, half_t* __restrict__ Wt,
                          int K, int Nc, int Ncp) {
    int idx = blockIdx.x * blockDim.x + threadIdx.x;
    if (idx >= Ncp * K) return;
    int n = idx / K, k = idx - n * K;
    Wt[idx] = (n < Nc) ? (half_t)W[(size_t)k * Nc + n] : (half_t)0.f;
}

// ------- aggregation (fp16 in, fp16 out): out[d] = dinv[d]*(sum dinv[s]*in[s] + dinv[d]*in[d]) ----

__global__ void aggh128_kernel(const half_t* __restrict__ in, half_t* __restrict__ out,
                               const int* __restrict__ row_ptr, const int* __restrict__ colidx,
                               const float* __restrict__ dinv, int n) {
    int node = blockIdx.x;
    int c = threadIdx.x;  // 64 lanes, 2 cols each
    float dv = dinv[node];
    h2 self = *(const h2*)(in + (size_t)node * 128 + 2 * c);
    float acc0 = dv * (float)self[0], acc1 = dv * (float)self[1];
    int beg = row_ptr[node], end = row_ptr[node + 1];
    for (int k = beg; k < end; ++k) {
        int s = colidx[k];
        float ds = dinv[s];
        h2 v = *(const h2*)(in + (size_t)s * 128 + 2 * c);
        acc0 = fmaf(ds, (float)v[0], acc0);
        acc1 = fmaf(ds, (float)v[1], acc1);
    }
    h2 r;
    r[0] = (half_t)(dv * acc0);
    r[1] = (half_t)(dv * acc1);
    *(h2*)(out + (size_t)node * 128 + 2 * c) = r;
}

__global__ void aggh64_kernel(const half_t* __restrict__ in, half_t* __restrict__ out,
                              const int* __restrict__ row_ptr, const int* __restrict__ colidx,
                              const float* __restrict__ dinv, int n) {
    int node = blockIdx.x;
    int c = threadIdx.x;
    float dv = dinv[node];
    float acc = dv * (float)in[(size_t)node * 64 + c];
    int beg = row_ptr[node], end = row_ptr[node + 1];
    for (int k = beg; k < end; ++k) {
        int s = colidx[k];
        acc = fmaf(dinv[s], (float)in[(size_t)s * 64 + c], acc);
    }
    out[(size_t)node * 64 + c] = (half_t)(dv * acc);
}

__global__ void aggh_softmax_kernel(const half_t* __restrict__ in, float* __restrict__ out,
                                    const int* __restrict__ row_ptr, const int* __restrict__ colidx,
                                    const float* __restrict__ dinv, const float* __restrict__ b4,
                                    int n) {
    int node = blockIdx.x;
    int c = threadIdx.x;  // 64 threads, 40 active
    float dv = dinv[node];
    float acc = 0.f;
    if (c < 40) acc = dv * (float)in[(size_t)node * 40 + c];
    int beg = row_ptr[node], end = row_ptr[node + 1];
    for (int k = beg; k < end; ++k) {
        int s = colidx[k];
        if (c < 40) acc = fmaf(dinv[s], (float)in[(size_t)s * 40 + c], acc);
    }
    float z = (c < 40) ? (dv * acc + b4[c]) : -INFINITY;
    float m = z;
#pragma unroll
    for (int off = 32; off > 0; off >>= 1) m = fmaxf(m, __shfl_xor(m, off, 64));
    float e = (c < 40) ? expf(z - m) : 0.f;
    float s = e;
#pragma unroll
    for (int off = 32; off > 0; off >>= 1) s += __shfl_xor(s, off, 64);
    if (c < 40) out[(size_t)node * 40 + c] = z - m - logf(s);
}

// ---------------- MFMA GEMM (unchanged from round 4) ----------------

template <int K, int NT, bool FUSE>
__global__ __launch_bounds__(256) void mgemm_kernel(const half_t* __restrict__ A,
                                                    const half_t* __restrict__ Wt,  // [NT*16][K]
                                                    const float* __restrict__ AB,
                                                    const float* __restrict__ pa,
                                                    half_t* __restrict__ C,
                                                    int M, int Nc) {
    int wave = threadIdx.x >> 6;
    int lane = threadIdx.x & 63;
    int r0 = blockIdx.x * 64 + wave * 16;
    int arow = r0 + (lane & 15);
    int kgrp = lane >> 4;
    float alpha = FUSE ? pa[0] : 0.f;

    h8 af[K / 32];
    bool rowok = (arow < M);
    const half_t* Ap = A + (size_t)arow * K + kgrp * 8;
#pragma unroll
    for (int kk = 0; kk < K / 32; ++kk) {
        h8 v;
        if (rowok) {
            v = *(const h8*)(Ap + kk * 32);
        } else {
#pragma unroll
            for (int j = 0; j < 8; ++j) v[j] = (half_t)0.f;
        }
        if (FUSE) {
            int kb = kk * 32 + kgrp * 8;
#pragma unroll
            for (int j = 0; j < 8; ++j) {
                float u = (float)v[j] * AB[kb + j] + AB[256 + kb + j];
                u = (u >= 0.f) ? u : alpha * u;
                v[j] = (half_t)u;
            }
        }
        af[kk] = v;
    }

#pragma unroll 1
    for (int nt = 0; nt < NT; ++nt) {
        f4 acc = {0.f, 0.f, 0.f, 0.f};
        const half_t* Wp = Wt + (size_t)(nt * 16 + (lane & 15)) * K + kgrp * 8;
#pragma unroll
        for (int kk = 0; kk < K / 32; ++kk) {
            h8 bf = *(const h8*)(Wp + kk * 32);
            acc = __builtin_amdgcn_mfma_f32_16x16x32_f16(af[kk], bf, acc, 0, 0, 0);
        }
        int col = nt * 16 + (lane & 15);
        if (col < Nc) {
#pragma unroll
            for (int j = 0; j < 4; ++j) {
                int row = r0 + kgrp * 4 + j;
                if (row < M) C[(size_t)row * Nc + col] = (half_t)acc[j];
            }
        }
    }
}

// ---------------- BatchNorm stats v2: vectorized h8 loads + LDS reduce + per-block atomics ----
// blockDim 256. Each thread owns one 8-column block, grid-strides over rows.

template <int F>
__global__ __launch_bounds__(256) void stats2_kernel(const half_t* __restrict__ z,
                                                     float* __restrict__ sums, int n) {
    constexpr int CB = F / 8;     // col-blocks per row
    constexpr int RG = 256 / CB;  // rows in flight per block
    __shared__ float red[256][16];
    int t = threadIdx.x;
    int cb = t % CB;
    int rg = t / CB;
    float sm[8], sq[8];
#pragma unroll
    for (int j = 0; j < 8; ++j) { sm[j] = 0.f; sq[j] = 0.f; }
    for (int r = blockIdx.x * RG + rg; r < n; r += gridDim.x * RG) {
        h8 v = *(const h8*)(z + (size_t)r * F + cb * 8);
#pragma unroll
        for (int j = 0; j < 8; ++j) {
            float f = (float)v[j];
            sm[j] += f;
            sq[j] = fmaf(f, f, sq[j]);
        }
    }
#pragma unroll
    for (int j = 0; j < 8; ++j) { red[t][j] = sm[j]; red[t][8 + j] = sq[j]; }
    __syncthreads();
    for (int o = t; o < 2 * F; o += 256) {
        int c = o % F, kind = o / F;
        int cbo = c >> 3, ci = (c & 7) + kind * 8;
        float v = 0.f;
#pragma unroll
        for (int g = 0; g < RG; ++g) v += red[g * CB + cbo][ci];
        atomicAdd(&sums[kind * 256 + c], v);
    }
}

__global__ void bnfin_kernel(const float* __restrict__ sums, const float* __restrict__ g,
                             const float* __restrict__ be, float* __restrict__ AB, int n, int F) {
    int c = threadIdx.x;
    if (c >= F) return;
    float mean = sums[c] / (float)n;
    float var = sums[256 + c] / (float)n - mean * mean;
    float rstd = rsqrtf(var + 1e-5f);
    float sc = g[c] * rstd;
    AB[c] = sc;
    AB[256 + c] = be[c] - mean * sc;
}

// ---------------- launch ----------------

extern "C" void kernel_launch(void* const* d_in, const int* in_sizes, int n_in,
                              void* d_out, int out_size, void* d_ws, size_t ws_size,
                              hipStream_t stream) {
    const float* x   = (const float*)d_in[0];
    const int*   ei  = (const int*)d_in[1];
    const float* W1  = (const float*)d_in[2];
    const float* g1  = (const float*)d_in[4];
    const float* be1 = (const float*)d_in[5];
    const float* W2  = (const float*)d_in[6];
    const float* g2  = (const float*)d_in[8];
    const float* be2 = (const float*)d_in[9];
    const float* W3  = (const float*)d_in[10];
    const float* g3  = (const float*)d_in[12];
    const float* be3 = (const float*)d_in[13];
    const float* W4  = (const float*)d_in[14];
    const float* b4  = (const float*)d_in[15];
    const float* pa  = (const float*)d_in[16];
    // b1,b2,b3 dropped: constants before BatchNorm cancel exactly in mean subtraction.

    int N = in_sizes[0] / 128;
    int E = in_sizes[1] / 2;

    char* ws = (char*)d_ws;
    size_t off = 0;
    auto carve = [&](size_t bytes) -> char* {
        char* p = ws + off;
        off += (bytes + 255) & ~(size_t)255;
        return p;
    };
    int nb = (N + SCAN_ELEMS - 1) / SCAN_ELEMS;
    float*  dinv    = (float*)carve((size_t)N * 4);
    int*    row_ptr = (int*)carve((size_t)(N + 1) * 4);
    int*    woff    = (int*)carve((size_t)N * 4);
    int*    counts  = (int*)carve((size_t)N * 4);
    int*    bsums   = (int*)carve((size_t)nb * 4);
    int*    colidx  = (int*)carve((size_t)E * 4);
    float*  stats   = (float*)carve(512 * 4);
    float*  bnAB    = (float*)carve(512 * 4);
    half_t* W1t     = (half_t*)carve((size_t)256 * 128 * 2);
    half_t* W2t     = (half_t*)carve((size_t)128 * 256 * 2);
    half_t* W3t     = (half_t*)carve((size_t)64 * 128 * 2);
    half_t* W4t     = (half_t*)carve((size_t)48 * 64 * 2);
    half_t* hA      = (half_t*)carve((size_t)N * 256 * 2);  // Z1
    half_t* hB      = (half_t*)carve((size_t)N * 128 * 2);  // xh, P2
    half_t* hC      = (half_t*)carve((size_t)N * 128 * 2);  // P1, Z2
    half_t* hD1     = (half_t*)carve((size_t)N * 64 * 2);   // P3
    half_t* hD2     = (half_t*)carve((size_t)N * 64 * 2);   // Z3
    half_t* hE      = (half_t*)carve((size_t)N * 40 * 2);   // P4
    (void)n_in; (void)out_size; (void)ws_size;

    // CSR build
    hipMemsetAsync(counts, 0, (size_t)N * 4, stream);
    count_kernel<<<(E + 255) / 256, 256, 0, stream>>>(ei, counts, E);
    partsum_kernel<<<nb, 256, 0, stream>>>(counts, bsums, N);
    basescan_kernel<<<1, 256, 0, stream>>>(bsums, row_ptr, nb, N);
    scanfill_kernel<<<nb, 256, 0, stream>>>(counts, bsums, row_ptr, woff, dinv, N);
    fill_kernel<<<(E + 255) / 256, 256, 0, stream>>>(ei, woff, colidx, E);

    // weight convert+transpose (fp16)
    wt_kernel<<<(256 * 128 + 255) / 256, 256, 0, stream>>>(W1, W1t, 128, 256, 256);
    wt_kernel<<<(128 * 256 + 255) / 256, 256, 0, stream>>>(W2, W2t, 256, 128, 128);
    wt_kernel<<<(64 * 128 + 255) / 256, 256, 0, stream>>>(W3, W3t, 128, 64, 64);
    wt_kernel<<<(48 * 64 + 255) / 256, 256, 0, stream>>>(W4, W4t, 64, 40, 48);

    int gb = (N + 63) / 64;  // mgemm blocks

    // L1: x->fp16, aggregate(128), MFMA GEMM -> Z1 fp16 [N,256]
    f2h_kernel<<<(N * 128 / 4 + 255) / 256, 256, 0, stream>>>(x, hB, N * 128 / 4);
    aggh128_kernel<<<N, 64, 0, stream>>>(hB, hC, row_ptr, colidx, dinv, N);
    mgemm_kernel<128, 16, false><<<gb, 256, 0, stream>>>(hC, W1t, nullptr, nullptr, hA, N, 256);
    hipMemsetAsync(stats, 0, 512 * 4, stream);
    stats2_kernel<256><<<512, 256, 0, stream>>>(hA, stats, N);
    bnfin_kernel<<<1, 256, 0, stream>>>(stats, g1, be1, bnAB, N, 256);

    // L2: GEMM (BN1+PReLU fused) -> P2 fp16 [N,128], aggregate -> Z2
    mgemm_kernel<256, 8, true><<<gb, 256, 0, stream>>>(hA, W2t, bnAB, pa, hB, N, 128);
    aggh128_kernel<<<N, 64, 0, stream>>>(hB, hC, row_ptr, colidx, dinv, N);
    hipMemsetAsync(stats, 0, 512 * 4, stream);
    stats2_kernel<128><<<512, 256, 0, stream>>>(hC, stats, N);
    bnfin_kernel<<<1, 256, 0, stream>>>(stats, g2, be2, bnAB, N, 128);

    // L3: GEMM (BN2 fused) -> P3 [N,64], aggregate -> Z3
    mgemm_kernel<128, 4, true><<<gb, 256, 0, stream>>>(hC, W3t, bnAB, pa, hD1, N, 64);
    aggh64_kernel<<<N, 64, 0, stream>>>(hD1, hD2, row_ptr, colidx, dinv, N);
    hipMemsetAsync(stats, 0, 512 * 4, stream);
    stats2_kernel<64><<<512, 256, 0, stream>>>(hD2, stats, N);
    bnfin_kernel<<<1, 256, 0, stream>>>(stats, g3, be3, bnAB, N, 64);

    // L4: GEMM (BN3 fused) -> P4 [N,40], aggregate + b4 + log_softmax -> out (f32)
    mgemm_kernel<64, 3, true><<<gb, 256, 0, stream>>>(hD2, W4t, bnAB, pa, hE, N, 40);
    aggh_softmax_kernel<<<N, 64, 0, stream>>>(hE, (float*)d_out, row_ptr, colidx, dinv, b4, N);
}